// Round 1
// baseline (1086.272 us; speedup 1.0000x reference)
//
#include <hip/hip_runtime.h>
#include <cfloat>

typedef _Float16 half8  __attribute__((ext_vector_type(8)));
typedef _Float16 half4v __attribute__((ext_vector_type(4)));

#define NBATCH 16
#define NSEQ   2048
#define ND     512
#define NC     8192
#define NTOK   (NBATCH * NSEQ)                 // 32768
#define MT     128
#define NT     128
#define BK     32
#define NCHUNK 8
#define CODES_PER_CHUNK (NC / NCHUNK)          // 1024
#define TILES_PER_CHUNK (CODES_PER_CHUNK / NT) // 8
#define KSTEPS (ND / BK)                       // 16
#define LDSP   (BK + 8)                        // 40 halves -> 80B row stride (16B aligned)

#define XSCALE 8.0f
#define ESCALE 64.0f
// acc = sum( (8x)*(64e) ) = 512*xy ; score = e2 - 2*xy = e2 - acc/256
#define SCORE_SCALE (2.0f / (XSCALE * ESCALE)) // 1/256

// ---------------- prep: split-convert embed (scaled by 64) to f16 h/l ----------------
__global__ __launch_bounds__(256) void prep_embed(const float* __restrict__ embed,
                                                  _Float16* __restrict__ eh,
                                                  _Float16* __restrict__ el) {
  int idx = blockIdx.x * 256 + threadIdx.x;
  int stride = gridDim.x * 256;
  for (int i = idx; i < NC * ND; i += stride) {
    float v = ESCALE * embed[i];
    _Float16 h = (_Float16)v;
    eh[i] = h;
    el[i] = (_Float16)(v - (float)h);
  }
}

// ---------------- prep: e2[c] = sum_d embed[c][d]^2 (fp32, unscaled) ----------------
__global__ __launch_bounds__(256) void prep_e2(const float* __restrict__ embed,
                                               float* __restrict__ e2) {
  int wave = threadIdx.x >> 6, lane = threadIdx.x & 63;
  int c = blockIdx.x * 4 + wave;
  const float* row = embed + (size_t)c * ND;
  float s = 0.f;
  for (int k = lane; k < ND; k += 64) { float v = row[k]; s = fmaf(v, v, s); }
  for (int off = 32; off > 0; off >>= 1) s += __shfl_down(s, off, 64);
  if (lane == 0) e2[c] = s;
}

// ---------------- fused GEMM + per-row argmin over a code chunk ----------------
__global__ __launch_bounds__(256, 2) void vq_argmin(
    const float* __restrict__ x, const int* __restrict__ len,
    const _Float16* __restrict__ eh, const _Float16* __restrict__ el,
    const float* __restrict__ e2g,
    float* __restrict__ pV, int* __restrict__ pI) {
  __shared__ _Float16 sXh[MT][LDSP];
  __shared__ _Float16 sXl[MT][LDSP];
  __shared__ _Float16 sEh[NT][LDSP];
  __shared__ _Float16 sEl[NT][LDSP];
  __shared__ float sRedV[MT][2];
  __shared__ int   sRedI[MT][2];
  __shared__ float sBestV[MT];
  __shared__ int   sBestI[MT];

  const int mt = blockIdx.x;      // 0..255 (token tile)
  const int chunk = blockIdx.y;   // 0..7  (code chunk)
  const int b  = mt >> 4;
  const int s0 = (mt & 15) * MT;
  if (s0 >= len[b]) return;       // whole tile masked -> nothing to compute
  const int row0 = mt * MT;

  const int tid  = threadIdx.x;
  const int wave = tid >> 6, lane = tid & 63;
  const int quad = lane >> 4, lid = lane & 15;
  const int wr = wave >> 1, wc = wave & 1;

  if (tid < MT) { sBestV[tid] = FLT_MAX; sBestI[tid] = 0; }

  typedef float floatx4 __attribute__((ext_vector_type(4)));

  for (int ct = 0; ct < TILES_PER_CHUNK; ++ct) {
    const int code0 = chunk * CODES_PER_CHUNK + ct * NT;
    floatx4 acc[4][4];
#pragma unroll
    for (int i = 0; i < 4; ++i)
#pragma unroll
      for (int j = 0; j < 4; ++j) acc[i][j] = (floatx4){0.f, 0.f, 0.f, 0.f};

    for (int kt = 0; kt < KSTEPS; ++kt) {
      __syncthreads();
      // ---- stage X tile (fp32 -> scaled f16 split), 128 rows x 32 k ----
#pragma unroll
      for (int it = 0; it < 4; ++it) {
        int f = it * 256 + tid;          // float4 granule id, 1024 total
        int r  = f >> 3;                 // 8 float4 per row
        int kq = (f & 7) << 2;
        const float4 v4 = *(const float4*)(x + (size_t)(row0 + r) * ND + kt * BK + kq);
        float vs[4] = {v4.x, v4.y, v4.z, v4.w};
        half4v hv, lv;
#pragma unroll
        for (int q = 0; q < 4; ++q) {
          float vv = XSCALE * vs[q];
          _Float16 h = (_Float16)vv;
          hv[q] = h;
          lv[q] = (_Float16)(vv - (float)h);
        }
        *(half4v*)&sXh[r][kq] = hv;
        *(half4v*)&sXl[r][kq] = lv;
      }
      // ---- stage E tile (preconverted f16 h/l), 128 codes x 32 k ----
#pragma unroll
      for (int it = 0; it < 2; ++it) {
        int g = it * 256 + tid;          // 16B granule id, 512 per array
        int r  = g >> 2;                 // 4 granules per row
        int kq = (g & 3) << 3;
        size_t src = (size_t)(code0 + r) * ND + kt * BK + kq;
        *(uint4*)&sEh[r][kq] = *(const uint4*)(eh + src);
        *(uint4*)&sEl[r][kq] = *(const uint4*)(el + src);
      }
      __syncthreads();
      // ---- one K32 MFMA step ----
      const int kb = quad * 8;
      half8 ah[4], al[4], bh[4], bl[4];
#pragma unroll
      for (int i = 0; i < 4; ++i) {
        ah[i] = *(const half8*)&sXh[wr * 64 + i * 16 + lid][kb];
        al[i] = *(const half8*)&sXl[wr * 64 + i * 16 + lid][kb];
      }
#pragma unroll
      for (int j = 0; j < 4; ++j) {
        bh[j] = *(const half8*)&sEh[wc * 64 + j * 16 + lid][kb];
        bl[j] = *(const half8*)&sEl[wc * 64 + j * 16 + lid][kb];
      }
#pragma unroll
      for (int i = 0; i < 4; ++i)
#pragma unroll
        for (int j = 0; j < 4; ++j) {
          acc[i][j] = __builtin_amdgcn_mfma_f32_16x16x32_f16(ah[i], bh[j], acc[i][j], 0, 0, 0);
          acc[i][j] = __builtin_amdgcn_mfma_f32_16x16x32_f16(ah[i], bl[j], acc[i][j], 0, 0, 0);
          acc[i][j] = __builtin_amdgcn_mfma_f32_16x16x32_f16(al[i], bh[j], acc[i][j], 0, 0, 0);
        }
    }

    // ---- epilogue: per-row argmin over this 128-code tile ----
    float e2v[4]; int cjv[4];
#pragma unroll
    for (int j = 0; j < 4; ++j) {
      cjv[j] = code0 + wc * 64 + j * 16 + lid;   // C/D layout: col = lane&15
      e2v[j] = e2g[cjv[j]];
    }
#pragma unroll
    for (int i = 0; i < 4; ++i) {
#pragma unroll
      for (int reg = 0; reg < 4; ++reg) {
        float best = fmaf(-SCORE_SCALE, acc[i][0][reg], e2v[0]);
        int bidx = cjv[0];
#pragma unroll
        for (int j = 1; j < 4; ++j) {
          float vj = fmaf(-SCORE_SCALE, acc[i][j][reg], e2v[j]);
          if (vj < best) { best = vj; bidx = cjv[j]; }   // ascending idx: strict < keeps first
        }
#pragma unroll
        for (int m = 1; m < 16; m <<= 1) {               // reduce across the 16 cols in-quad
          float ov = __shfl_xor(best, m, 64);
          int   oi = __shfl_xor(bidx, m, 64);
          if (ov < best || (ov == best && oi < bidx)) { best = ov; bidx = oi; }
        }
        if (lid == 0) {
          int row = wr * 64 + i * 16 + quad * 4 + reg;   // C/D layout: row = quad*4+reg
          sRedV[row][wc] = best;
          sRedI[row][wc] = bidx;
        }
      }
    }
    __syncthreads();
    if (tid < MT) {
      float v0 = sRedV[tid][0]; int i0 = sRedI[tid][0];
      float v1 = sRedV[tid][1]; int i1 = sRedI[tid][1];
      if (v1 < v0) { v0 = v1; i0 = i1; }                 // wc=0 holds lower codes: tie keeps it
      if (v0 < sBestV[tid]) { sBestV[tid] = v0; sBestI[tid] = i0; }  // later tiles = higher codes
    }
  }
  __syncthreads();
  if (tid < MT) {
    int t = row0 + tid;
    pV[chunk * NTOK + t] = sBestV[tid];
    pI[chunk * NTOK + t] = sBestI[tid];
  }
}

// ---------------- combine partials, gather code rows, apply mask ----------------
__global__ __launch_bounds__(256) void vq_output(
    const float* __restrict__ embed, const int* __restrict__ len,
    const float* __restrict__ pV, const int* __restrict__ pI,
    float* __restrict__ out) {
  int wave = threadIdx.x >> 6, lane = threadIdx.x & 63;
  int t = blockIdx.x * 4 + wave;
  int b = t >> 11, s = t & (NSEQ - 1);
  float* outq = out + (size_t)t * ND;
  float* outind = out + (size_t)NTOK * ND;
  if (s >= len[b]) {
    float4 z = {0.f, 0.f, 0.f, 0.f};
    *(float4*)&outq[lane * 8]     = z;
    *(float4*)&outq[lane * 8 + 4] = z;
    if (lane == 0) outind[t] = -1.0f;
    return;
  }
  float bv = pV[t]; int bi = pI[t];
#pragma unroll
  for (int c = 1; c < NCHUNK; ++c) {
    float v = pV[c * NTOK + t];
    int i2  = pI[c * NTOK + t];
    if (v < bv) { bv = v; bi = i2; }      // lower chunk = lower codes: tie keeps it
  }
  const float* er = embed + (size_t)bi * ND;
  *(float4*)&outq[lane * 8]     = *(const float4*)&er[lane * 8];
  *(float4*)&outq[lane * 8 + 4] = *(const float4*)&er[lane * 8 + 4];
  if (lane == 0) outind[t] = (float)bi;
}

extern "C" void kernel_launch(void* const* d_in, const int* in_sizes, int n_in,
                              void* d_out, int out_size, void* d_ws, size_t ws_size,
                              hipStream_t stream) {
  const float* x     = (const float*)d_in[0];
  const int*   lenp  = (const int*)d_in[1];
  const float* embed = (const float*)d_in[2];
  float* out = (float*)d_out;

  // ws layout: eh (8MB) | el (8MB) | e2 (32KB) | pV (1MB) | pI (1MB)  ~ 18.9 MB
  char* w = (char*)d_ws;
  _Float16* eh = (_Float16*)w;
  _Float16* el = (_Float16*)(w + (size_t)NC * ND * 2);
  float*    e2 = (float*)(w + (size_t)NC * ND * 4);
  float*    pV = (float*)(w + (size_t)NC * ND * 4 + NC * 4);
  int*      pI = (int*)(w + (size_t)NC * ND * 4 + NC * 4 + (size_t)NCHUNK * NTOK * 4);

  prep_embed<<<2048, 256, 0, stream>>>(embed, eh, el);
  prep_e2<<<NC / 4, 256, 0, stream>>>(embed, e2);
  dim3 grid(NTOK / MT, NCHUNK);
  vq_argmin<<<grid, 256, 0, stream>>>(x, lenp, eh, el, e2, pV, pI);
  vq_output<<<NTOK / 4, 256, 0, stream>>>(embed, lenp, pV, pI, out);
}

// Round 2
// 911.593 us; speedup vs baseline: 1.1916x; 1.1916x over previous
//
#include <hip/hip_runtime.h>
#include <cfloat>

typedef _Float16 half8  __attribute__((ext_vector_type(8)));
typedef _Float16 half4v __attribute__((ext_vector_type(4)));
typedef float floatx4 __attribute__((ext_vector_type(4)));

#define NBATCH 16
#define NSEQ   2048
#define ND     512
#define NC     8192
#define NTOK   (NBATCH * NSEQ)                 // 32768
#define MT     128
#define NT     128
#define BK     32
#define NCHUNK 8
#define CODES_PER_CHUNK (NC / NCHUNK)          // 1024
#define TILES_PER_CHUNK (CODES_PER_CHUNK / NT) // 8
#define KSTEPS (ND / BK)                       // 16

#define XSCALE 8.0f
#define ESCALE 64.0f
// acc = sum( (8x)*(64e) ) = 512*xy ; score = e2 - 2*xy = e2 - acc/256
#define SCORE_SCALE (2.0f / (XSCALE * ESCALE)) // 1/256

typedef const void __attribute__((address_space(1)))* gp_t;
typedef void       __attribute__((address_space(3)))* lp_t;
__device__ __forceinline__ void cp16(lp_t l, gp_t g) {
  // async global->LDS DMA, 16B per lane, LDS dst = wave-uniform base + lane*16
  __builtin_amdgcn_global_load_lds(g, l, 16, 0, 0);
}

// ---------------- prep: split-convert embed (scaled by 64) to f16 h/l ----------------
__global__ __launch_bounds__(256) void prep_embed(const float* __restrict__ embed,
                                                  _Float16* __restrict__ eh,
                                                  _Float16* __restrict__ el) {
  int idx = blockIdx.x * 256 + threadIdx.x;
  int stride = gridDim.x * 256;
  for (int i = idx; i < NC * ND; i += stride) {
    float v = ESCALE * embed[i];
    _Float16 h = (_Float16)v;
    eh[i] = h;
    el[i] = (_Float16)(v - (float)h);
  }
}

// ---------------- prep: split-convert x (scaled by 8) to f16 h/l ----------------
__global__ __launch_bounds__(256) void prep_x(const float* __restrict__ x,
                                              _Float16* __restrict__ xh,
                                              _Float16* __restrict__ xl) {
  int idx = blockIdx.x * 256 + threadIdx.x;
  int stride = gridDim.x * 256;
  const int n4 = NTOK * ND / 4;
  for (int i = idx; i < n4; i += stride) {
    float4 v = ((const float4*)x)[i];
    float vs[4] = {v.x, v.y, v.z, v.w};
    half4v h, l;
#pragma unroll
    for (int q = 0; q < 4; ++q) {
      float vv = XSCALE * vs[q];
      _Float16 hh = (_Float16)vv;
      h[q] = hh;
      l[q] = (_Float16)(vv - (float)hh);
    }
    ((half4v*)xh)[i] = h;
    ((half4v*)xl)[i] = l;
  }
}

// ---------------- prep: e2[c] = sum_d embed[c][d]^2 (fp32, unscaled) ----------------
__global__ __launch_bounds__(256) void prep_e2(const float* __restrict__ embed,
                                               float* __restrict__ e2) {
  int wave = threadIdx.x >> 6, lane = threadIdx.x & 63;
  int c = blockIdx.x * 4 + wave;
  const float* row = embed + (size_t)c * ND;
  float s = 0.f;
  for (int k = lane; k < ND; k += 64) { float v = row[k]; s = fmaf(v, v, s); }
  for (int off = 32; off > 0; off >>= 1) s += __shfl_down(s, off, 64);
  if (lane == 0) e2[c] = s;
}

// ---------------- fused GEMM + per-row argmin over a code chunk ----------------
// LDS layout: flat [128 rows][4 granules of 8 halves]; granule (r, cl) holds
// global column-granule (cl ^ ((r>>1)&3)) -> conflict-free ds_read_b128 AND
// compatible with global_load_lds's lane-ordered LDS writes.
template <bool PREX>
__global__ __launch_bounds__(256, 3) void vq_argmin(
    const float* __restrict__ x,
    const _Float16* __restrict__ xh, const _Float16* __restrict__ xl,
    const int* __restrict__ len,
    const _Float16* __restrict__ eh, const _Float16* __restrict__ el,
    const float* __restrict__ e2g,
    float* __restrict__ pV, int* __restrict__ pI) {
  __shared__ _Float16 sXh[MT * BK];
  __shared__ _Float16 sXl[MT * BK];
  __shared__ _Float16 sEh[NT * BK];
  __shared__ _Float16 sEl[NT * BK];
  __shared__ float sRedV[MT][2];
  __shared__ int   sRedI[MT][2];
  __shared__ float sBestV[MT];
  __shared__ int   sBestI[MT];

  const int bx = blockIdx.x;
  const int b = bx & 15, stile = bx >> 4;   // b-major-last: spreads masked blocks
  if (stile * MT >= len[b]) return;
  const int row0 = b * NSEQ + stile * MT;
  const int chunk = blockIdx.y;

  const int tid  = threadIdx.x;
  const int wave = tid >> 6, lane = tid & 63;
  const int quad = lane >> 4, lid = lane & 15;
  const int wr = wave >> 1, wc = wave & 1;

  if (tid < MT) { sBestV[tid] = FLT_MAX; sBestI[tid] = 0; }

  // ---- staging geometry (granule = 16B = 8 halves) ----
  const int r0   = tid >> 2;                  // granule row for it=0 (it=1: +64)
  const int cl   = tid & 3;                   // lds col-granule
  const int csrc = cl ^ ((tid >> 3) & 3);     // swizzled source col-granule
  const int ldsg0 = (wave * 64) * 8;          // it=0 wave-uniform base (halves)
  const int ldsg1 = (256 + wave * 64) * 8;    // it=1

  // ---- fragment read offsets (halves); swizzle folds to a thread constant ----
  const int cswz = quad ^ ((lid >> 1) & 3);
  int aoff[4], boff[4];
#pragma unroll
  for (int i = 0; i < 4; ++i) aoff[i] = (wr * 64 + i * 16 + lid) * BK + cswz * 8;
#pragma unroll
  for (int j = 0; j < 4; ++j) boff[j] = (wc * 64 + j * 16 + lid) * BK + cswz * 8;

  const _Float16* pxh = PREX ? xh + (size_t)(row0 + r0) * ND + csrc * 8 : nullptr;
  const _Float16* pxl = PREX ? xl + (size_t)(row0 + r0) * ND + csrc * 8 : nullptr;
  const float*    pxf = x + (size_t)(row0 + r0) * ND + csrc * 8;

  for (int ct = 0; ct < TILES_PER_CHUNK; ++ct) {
    const int code0 = chunk * CODES_PER_CHUNK + ct * NT;
    const _Float16* peh = eh + (size_t)(code0 + r0) * ND + csrc * 8;
    const _Float16* pel = el + (size_t)(code0 + r0) * ND + csrc * 8;

    floatx4 acc[4][4];
#pragma unroll
    for (int i = 0; i < 4; ++i)
#pragma unroll
      for (int j = 0; j < 4; ++j) acc[i][j] = (floatx4){0.f, 0.f, 0.f, 0.f};

    int koff = 0;
    for (int kt = 0; kt < KSTEPS; ++kt, koff += BK) {
      __syncthreads();   // previous iteration's ds_reads done before overwrite
      if (PREX) {
        cp16((lp_t)&sXh[ldsg0], (gp_t)(pxh + koff));
        cp16((lp_t)&sXh[ldsg1], (gp_t)(pxh + 64 * ND + koff));
        cp16((lp_t)&sXl[ldsg0], (gp_t)(pxl + koff));
        cp16((lp_t)&sXl[ldsg1], (gp_t)(pxl + 64 * ND + koff));
      } else {
#pragma unroll
        for (int it = 0; it < 2; ++it) {
          const float* s = pxf + it * 64 * ND + koff;
          float4 a = *(const float4*)s;
          float4 c = *(const float4*)(s + 4);
          float vs[8] = {a.x, a.y, a.z, a.w, c.x, c.y, c.z, c.w};
          half8 h, l;
#pragma unroll
          for (int q = 0; q < 8; ++q) {
            float vv = XSCALE * vs[q];
            _Float16 hh = (_Float16)vv;
            h[q] = hh;
            l[q] = (_Float16)(vv - (float)hh);
          }
          *(half8*)&sXh[(it * 256 + tid) * 8] = h;
          *(half8*)&sXl[(it * 256 + tid) * 8] = l;
        }
      }
      cp16((lp_t)&sEh[ldsg0], (gp_t)(peh + koff));
      cp16((lp_t)&sEh[ldsg1], (gp_t)(peh + 64 * ND + koff));
      cp16((lp_t)&sEl[ldsg0], (gp_t)(pel + koff));
      cp16((lp_t)&sEl[ldsg1], (gp_t)(pel + 64 * ND + koff));
      __syncthreads();   // barrier drains vmcnt -> staged data visible

      half8 bhv[4], blv[4];
#pragma unroll
      for (int j = 0; j < 4; ++j) {
        bhv[j] = *(const half8*)&sEh[boff[j]];
        blv[j] = *(const half8*)&sEl[boff[j]];
      }
#pragma unroll
      for (int i = 0; i < 4; ++i) {
        half8 ahv = *(const half8*)&sXh[aoff[i]];
        half8 alv = *(const half8*)&sXl[aoff[i]];
#pragma unroll
        for (int j = 0; j < 4; ++j) {
          acc[i][j] = __builtin_amdgcn_mfma_f32_16x16x32_f16(ahv, bhv[j], acc[i][j], 0, 0, 0);
          acc[i][j] = __builtin_amdgcn_mfma_f32_16x16x32_f16(ahv, blv[j], acc[i][j], 0, 0, 0);
          acc[i][j] = __builtin_amdgcn_mfma_f32_16x16x32_f16(alv, bhv[j], acc[i][j], 0, 0, 0);
        }
      }
    }

    // ---- epilogue: per-row argmin over this 128-code tile ----
    float e2v[4]; int cjv[4];
#pragma unroll
    for (int j = 0; j < 4; ++j) {
      cjv[j] = code0 + wc * 64 + j * 16 + lid;   // C/D layout: col = lane&15
      e2v[j] = e2g[cjv[j]];
    }
#pragma unroll
    for (int i = 0; i < 4; ++i) {
#pragma unroll
      for (int reg = 0; reg < 4; ++reg) {
        float best = fmaf(-SCORE_SCALE, acc[i][0][reg], e2v[0]);
        int bidx = cjv[0];
#pragma unroll
        for (int j = 1; j < 4; ++j) {
          float vj = fmaf(-SCORE_SCALE, acc[i][j][reg], e2v[j]);
          if (vj < best) { best = vj; bidx = cjv[j]; }   // ascending idx: strict < keeps first
        }
#pragma unroll
        for (int m = 1; m < 16; m <<= 1) {               // reduce across the 16 cols in-quad
          float ov = __shfl_xor(best, m, 64);
          int   oi = __shfl_xor(bidx, m, 64);
          if (ov < best || (ov == best && oi < bidx)) { best = ov; bidx = oi; }
        }
        if (lid == 0) {
          int row = wr * 64 + i * 16 + quad * 4 + reg;   // C/D layout: row = quad*4+reg
          sRedV[row][wc] = best;
          sRedI[row][wc] = bidx;
        }
      }
    }
    __syncthreads();
    if (tid < MT) {
      float v0 = sRedV[tid][0]; int i0 = sRedI[tid][0];
      float v1 = sRedV[tid][1]; int i1 = sRedI[tid][1];
      if (v1 < v0) { v0 = v1; i0 = i1; }                 // wc=0 holds lower codes: tie keeps it
      if (v0 < sBestV[tid]) { sBestV[tid] = v0; sBestI[tid] = i0; }  // later tiles = higher codes
    }
  }
  __syncthreads();
  if (tid < MT) {
    int t = row0 + tid;
    pV[chunk * NTOK + t] = sBestV[tid];
    pI[chunk * NTOK + t] = sBestI[tid];
  }
}

// ---------------- combine partials, gather code rows, apply mask ----------------
__global__ __launch_bounds__(256) void vq_output(
    const float* __restrict__ embed, const int* __restrict__ len,
    const float* __restrict__ pV, const int* __restrict__ pI,
    float* __restrict__ out) {
  int wave = threadIdx.x >> 6, lane = threadIdx.x & 63;
  int t = blockIdx.x * 4 + wave;
  int b = t >> 11, s = t & (NSEQ - 1);
  float* outq = out + (size_t)t * ND;
  float* outind = out + (size_t)NTOK * ND;
  if (s >= len[b]) {
    float4 z = {0.f, 0.f, 0.f, 0.f};
    *(float4*)&outq[lane * 8]     = z;
    *(float4*)&outq[lane * 8 + 4] = z;
    if (lane == 0) outind[t] = -1.0f;
    return;
  }
  float bv = pV[t]; int bi = pI[t];
#pragma unroll
  for (int c = 1; c < NCHUNK; ++c) {
    float v = pV[c * NTOK + t];
    int i2  = pI[c * NTOK + t];
    if (v < bv) { bv = v; bi = i2; }      // lower chunk = lower codes: tie keeps it
  }
  const float* er = embed + (size_t)bi * ND;
  *(float4*)&outq[lane * 8]     = *(const float4*)&er[lane * 8];
  *(float4*)&outq[lane * 8 + 4] = *(const float4*)&er[lane * 8 + 4];
  if (lane == 0) outind[t] = (float)bi;
}

extern "C" void kernel_launch(void* const* d_in, const int* in_sizes, int n_in,
                              void* d_out, int out_size, void* d_ws, size_t ws_size,
                              hipStream_t stream) {
  const float* x     = (const float*)d_in[0];
  const int*   lenp  = (const int*)d_in[1];
  const float* embed = (const float*)d_in[2];
  float* out = (float*)d_out;

  // ws layout: eh (8MB) | el (8MB) | e2 (32KB) | pV (1MB) | pI (1MB) | xh (32MB) | xl (32MB)
  char* w = (char*)d_ws;
  size_t off = 0;
  _Float16* eh = (_Float16*)(w + off); off += (size_t)NC * ND * 2;
  _Float16* el = (_Float16*)(w + off); off += (size_t)NC * ND * 2;
  float*    e2 = (float*)(w + off);    off += (size_t)NC * 4;
  float*    pV = (float*)(w + off);    off += (size_t)NCHUNK * NTOK * 4;
  int*      pI = (int*)(w + off);      off += (size_t)NCHUNK * NTOK * 4;
  _Float16* xh = (_Float16*)(w + off); off += (size_t)NTOK * ND * 2;
  _Float16* xl = (_Float16*)(w + off); off += (size_t)NTOK * ND * 2;
  const bool prex = ws_size >= off;    // ws_size constant per session -> same path every call

  prep_embed<<<2048, 256, 0, stream>>>(embed, eh, el);
  prep_e2<<<NC / 4, 256, 0, stream>>>(embed, e2);
  dim3 grid(NTOK / MT, NCHUNK);
  if (prex) {
    prep_x<<<4096, 256, 0, stream>>>(x, xh, xl);
    vq_argmin<true><<<grid, 256, 0, stream>>>(x, xh, xl, lenp, eh, el, e2, pV, pI);
  } else {
    vq_argmin<false><<<grid, 256, 0, stream>>>(x, xh, xl, lenp, eh, el, e2, pV, pI);
  }
  vq_output<<<NTOK / 4, 256, 0, stream>>>(embed, lenp, pV, pI, out);
}